// Round 1
// baseline (2655.065 us; speedup 1.0000x reference)
//
#include <hip/hip_runtime.h>
#include <cstdint>
#include <cstddef>

#define B_ROWS 16384
#define D_DIM  512
#define NTXT_N 4096
#define H_DIM  1024

// ---------------- init: zero the acc counter ----------------
__global__ void init_kernel(int* acc) {
    if (threadIdx.x == 0 && blockIdx.x == 0) *acc = 0;
}

// ---------------- transpose: txt [512,4096] -> xt chunk [CH,512] ----------------
__global__ void transpose_kernel(const float* __restrict__ in, float* __restrict__ out, int n0)
{
    __shared__ float tile[32][33];
    const int nb = n0 + blockIdx.x * 32;   // col of `in` (txt index)
    const int db = blockIdx.y * 32;        // row of `in` (feature dim)
    const int tx = threadIdx.x, ty = threadIdx.y; // (32,8)
    #pragma unroll
    for (int j = 0; j < 32; j += 8)
        tile[ty + j][tx] = in[(size_t)(db + ty + j) * NTXT_N + nb + tx];
    __syncthreads();
    #pragma unroll
    for (int j = 0; j < 32; j += 8)
        out[(size_t)(blockIdx.x * 32 + ty + j) * D_DIM + db + tx] = tile[tx][ty + j];
}

// ---------------- tiled f32 GEMM:  C = act(A @ B (+bias)) ----------------
// A: [M,K] row-major.  B: BT ? [N,K] : [K,N] row-major.  C: [M,N].
// BM=BN=128, BK=16, 256 threads, 8x8 microtile.
template<bool BT, bool RELU, bool BIAS>
__global__ __launch_bounds__(256, 2) void gemm_kernel(
    const float* __restrict__ A, const float* __restrict__ Bm,
    const float* __restrict__ bias, float* __restrict__ C,
    int M, int N, int K)
{
    constexpr int BKt = 16;
    __shared__ float As[BKt][128 + 4];
    __shared__ float Bs[BKt][128 + 4];
    const int tid = threadIdx.x;
    const int bm  = blockIdx.y * 128;
    const int bn  = blockIdx.x * 128;
    const int tm  = (tid >> 4) * 8;
    const int tn  = (tid & 15) * 8;
    const int ar  = tid >> 2;         // 0..63
    const int ac  = (tid & 3) << 2;   // 0,4,8,12
    const int bk  = tid >> 5;         // 0..7
    const int bnn = (tid & 31) << 2;  // 0..124

    float acc[8][8] = {};

    for (int k0 = 0; k0 < K; k0 += BKt) {
        float4 a0 = *(const float4*)&A[(size_t)(bm + ar)      * K + k0 + ac];
        float4 a1 = *(const float4*)&A[(size_t)(bm + ar + 64) * K + k0 + ac];
        float4 b0, b1;
        if (BT) {
            b0 = *(const float4*)&Bm[(size_t)(bn + ar)      * K + k0 + ac];
            b1 = *(const float4*)&Bm[(size_t)(bn + ar + 64) * K + k0 + ac];
        } else {
            b0 = *(const float4*)&Bm[(size_t)(k0 + bk)     * N + bn + bnn];
            b1 = *(const float4*)&Bm[(size_t)(k0 + bk + 8) * N + bn + bnn];
        }
        __syncthreads();   // previous tile fully consumed
        As[ac + 0][ar] = a0.x; As[ac + 1][ar] = a0.y; As[ac + 2][ar] = a0.z; As[ac + 3][ar] = a0.w;
        As[ac + 0][ar + 64] = a1.x; As[ac + 1][ar + 64] = a1.y; As[ac + 2][ar + 64] = a1.z; As[ac + 3][ar + 64] = a1.w;
        if (BT) {
            Bs[ac + 0][ar] = b0.x; Bs[ac + 1][ar] = b0.y; Bs[ac + 2][ar] = b0.z; Bs[ac + 3][ar] = b0.w;
            Bs[ac + 0][ar + 64] = b1.x; Bs[ac + 1][ar + 64] = b1.y; Bs[ac + 2][ar + 64] = b1.z; Bs[ac + 3][ar + 64] = b1.w;
        } else {
            *(float4*)&Bs[bk][bnn]     = b0;
            *(float4*)&Bs[bk + 8][bnn] = b1;
        }
        __syncthreads();
        #pragma unroll
        for (int k = 0; k < BKt; ++k) {
            float a[8], b[8];
            *(float4*)&a[0] = *(const float4*)&As[k][tm];
            *(float4*)&a[4] = *(const float4*)&As[k][tm + 4];
            *(float4*)&b[0] = *(const float4*)&Bs[k][tn];
            *(float4*)&b[4] = *(const float4*)&Bs[k][tn + 4];
            #pragma unroll
            for (int i = 0; i < 8; ++i)
                #pragma unroll
                for (int j = 0; j < 8; ++j)
                    acc[i][j] = fmaf(a[i], b[j], acc[i][j]);
        }
    }

    #pragma unroll
    for (int i = 0; i < 8; ++i) {
        #pragma unroll
        for (int j = 0; j < 8; ++j) {
            float v = acc[i][j];
            if (BIAS) v += bias[bn + tn + j];
            if (RELU) v = fmaxf(v, 0.0f);
            acc[i][j] = v;
        }
        *(float4*)&C[(size_t)(bm + tm + i) * N + bn + tn]     = *(float4*)&acc[i][0];
        *(float4*)&C[(size_t)(bm + tm + i) * N + bn + tn + 4] = *(float4*)&acc[i][4];
    }
}

// ---------------- per-row reduction over one sim chunk ----------------
// For each row: ss=sum(raw^2), (mx,mi)=first-argmax, then
// x_j = raw_j * Cv with Cv = 1/(sqrt(ss)*n2*temp);  lse = max_x + log(sum exp(x-max_x))
// perrow = lse - raw[tgt]*Cv ;  acc += (argmax == tgt)
__global__ __launch_bounds__(256) void rowreduce_kernel(
    const float* __restrict__ sim, const int* __restrict__ tgt,
    const float* __restrict__ temp_p, float* __restrict__ perrow,
    int* __restrict__ acc_cnt, int row0)
{
    const int row = blockIdx.x;
    const float* srow = sim + (size_t)row * NTXT_N;
    const int tid = threadIdx.x;

    float v[16];
    #pragma unroll
    for (int q = 0; q < 4; ++q) {
        float4 f = *(const float4*)&srow[4 * tid + 1024 * q];
        v[4 * q + 0] = f.x; v[4 * q + 1] = f.y; v[4 * q + 2] = f.z; v[4 * q + 3] = f.w;
    }

    float ss = 0.0f, mx = -3.4e38f; int mi = 0x7fffffff;
    #pragma unroll
    for (int q = 0; q < 4; ++q)
        #pragma unroll
        for (int r = 0; r < 4; ++r) {
            const int j = 4 * tid + 1024 * q + r;
            const float x = v[4 * q + r];
            ss = fmaf(x, x, ss);
            if (x > mx) { mx = x; mi = j; }
            else if (x == mx && j < mi) mi = j;
        }

    #pragma unroll
    for (int off = 32; off; off >>= 1) {
        ss += __shfl_down(ss, off);
        const float omx = __shfl_down(mx, off);
        const int   omi = __shfl_down(mi, off);
        if (omx > mx || (omx == mx && omi < mi)) { mx = omx; mi = omi; }
    }

    __shared__ float sws[4], swm[4];
    __shared__ int   swi[4];
    __shared__ float bC, bMx;
    __shared__ int   bAmax;
    const int w = tid >> 6, lane = tid & 63;
    if (lane == 0) { sws[w] = ss; swm[w] = mx; swi[w] = mi; }
    __syncthreads();
    if (tid == 0) {
        float tss = 0.0f, tmx = -3.4e38f; int tmi = 0x7fffffff;
        #pragma unroll
        for (int i = 0; i < 4; ++i) {
            tss += sws[i];
            if (swm[i] > tmx || (swm[i] == tmx && swi[i] < tmi)) { tmx = swm[i]; tmi = swi[i]; }
        }
        const float inv_nr = 1.0f / sqrtf(tss);
        const float n2 = sqrtf(tss * inv_nr * inv_nr);   // ~= 1, faithful to reference
        const float Cv = inv_nr / (n2 * temp_p[0]);
        bC = Cv; bMx = tmx * Cv; bAmax = tmi;
    }
    __syncthreads();
    const float Cv = bC, mxx = bMx;

    float es = 0.0f;
    #pragma unroll
    for (int q = 0; q < 16; ++q) es += expf(v[q] * Cv - mxx);
    #pragma unroll
    for (int off = 32; off; off >>= 1) es += __shfl_down(es, off);
    if (lane == 0) sws[w] = es;
    __syncthreads();
    if (tid == 0) {
        const float tes = sws[0] + sws[1] + sws[2] + sws[3];
        const float lse = mxx + logf(tes);
        const int t = tgt[row0 + row];
        const float rawt = srow[t];
        perrow[row0 + row] = lse - rawt * Cv;
        if (bAmax == t) atomicAdd(acc_cnt, 1);
    }
}

// ---------------- finalize: loss = mean(perrow), out[1] = acc ----------------
__global__ __launch_bounds__(256) void finalize_kernel(
    const float* __restrict__ perrow, const int* __restrict__ acc_cnt,
    float* __restrict__ out)
{
    __shared__ float red[256];
    const int tid = threadIdx.x;
    float s = 0.0f;
    for (int i = tid; i < B_ROWS; i += 256) s += perrow[i];
    red[tid] = s;
    __syncthreads();
    for (int st = 128; st; st >>= 1) {
        if (tid < st) red[tid] += red[tid + st];
        __syncthreads();
    }
    if (tid == 0) {
        out[0] = red[0] / (float)B_ROWS;
        out[1] = (float)(*acc_cnt);
    }
}

extern "C" void kernel_launch(void* const* d_in, const int* in_sizes, int n_in,
                              void* d_out, int out_size, void* d_ws, size_t ws_size,
                              hipStream_t stream)
{
    const float* img  = (const float*)d_in[0];
    const float* txt  = (const float*)d_in[1];
    const int*   tgt  = (const int*)  d_in[2];
    const float* temp = (const float*)d_in[3];
    const float* Wi0 = (const float*)d_in[4];
    const float* bi0 = (const float*)d_in[5];
    const float* Wi1 = (const float*)d_in[6];
    const float* bi1 = (const float*)d_in[7];
    const float* Wi2 = (const float*)d_in[8];
    const float* bi2 = (const float*)d_in[9];
    const float* Wt0 = (const float*)d_in[10];
    const float* bt0 = (const float*)d_in[11];
    const float* Wt1 = (const float*)d_in[12];
    const float* bt1 = (const float*)d_in[13];
    const float* Wt2 = (const float*)d_in[14];
    const float* bt2 = (const float*)d_in[15];
    float* out = (float*)d_out;

    // choose chunk sizes by available workspace
    const size_t wsf_n = ws_size / sizeof(float);
    int CH = 4096, SIMCH = 2048;
    auto need = [&](int ch, int sc) -> size_t {
        return (size_t)2 * ch * H_DIM + (size_t)NTXT_N * D_DIM + (size_t)ch * D_DIM
             + (size_t)sc * NTXT_N + B_ROWS + 16;
    };
    while (CH > 512 && need(CH, SIMCH) > wsf_n) { CH >>= 1; SIMCH >>= 1; }

    float* wsf    = (float*)d_ws;
    float* REG_A  = wsf;
    float* REG_B  = REG_A + (size_t)CH * H_DIM;
    float* P_TXT  = REG_B + (size_t)CH * H_DIM;
    float* S1     = P_TXT + (size_t)NTXT_N * D_DIM;   // xt chunk, then p_img chunk
    float* SIM    = S1 + (size_t)CH * D_DIM;
    float* PERROW = SIM + (size_t)SIMCH * NTXT_N;
    int*   ACC    = (int*)(PERROW + B_ROWS);

    init_kernel<<<1, 64, 0, stream>>>(ACC);

    // ---- txt MLP:  p_txt = MLP(txt^T) ----
    for (int n0 = 0; n0 < NTXT_N; n0 += CH) {
        transpose_kernel<<<dim3(CH / 32, D_DIM / 32), dim3(32, 8), 0, stream>>>(txt, S1, n0);
        gemm_kernel<false, true,  true><<<dim3(H_DIM / 128, CH / 128), 256, 0, stream>>>(
            S1, Wt0, bt0, REG_A, CH, H_DIM, D_DIM);
        gemm_kernel<false, true,  true><<<dim3(H_DIM / 128, CH / 128), 256, 0, stream>>>(
            REG_A, Wt1, bt1, REG_B, CH, H_DIM, H_DIM);
        gemm_kernel<false, false, true><<<dim3(D_DIM / 128, CH / 128), 256, 0, stream>>>(
            REG_B, Wt2, bt2, P_TXT + (size_t)n0 * D_DIM, CH, D_DIM, H_DIM);
    }

    // ---- img MLP + fused sim/loss, chunked over rows ----
    for (int m0 = 0; m0 < B_ROWS; m0 += CH) {
        gemm_kernel<false, true,  true><<<dim3(H_DIM / 128, CH / 128), 256, 0, stream>>>(
            img + (size_t)m0 * D_DIM, Wi0, bi0, REG_A, CH, H_DIM, D_DIM);
        gemm_kernel<false, true,  true><<<dim3(H_DIM / 128, CH / 128), 256, 0, stream>>>(
            REG_A, Wi1, bi1, REG_B, CH, H_DIM, H_DIM);
        gemm_kernel<false, false, true><<<dim3(D_DIM / 128, CH / 128), 256, 0, stream>>>(
            REG_B, Wi2, bi2, S1, CH, D_DIM, H_DIM);
        for (int s0 = 0; s0 < CH; s0 += SIMCH) {
            gemm_kernel<true, false, false><<<dim3(NTXT_N / 128, SIMCH / 128), 256, 0, stream>>>(
                S1 + (size_t)s0 * D_DIM, P_TXT, nullptr, SIM, SIMCH, NTXT_N, D_DIM);
            rowreduce_kernel<<<SIMCH, 256, 0, stream>>>(
                SIM, tgt, temp, PERROW, ACC, m0 + s0);
        }
    }

    finalize_kernel<<<1, 256, 0, stream>>>(PERROW, ACC, out);
}

// Round 2
// 1040.094 us; speedup vs baseline: 2.5527x; 2.5527x over previous
//
#include <hip/hip_runtime.h>
#include <cstdint>
#include <cstddef>

#define B_ROWS 16384
#define D_DIM  512
#define NTXT_N 4096
#define H_DIM  1024

typedef __attribute__((ext_vector_type(8))) short short8;
typedef __attribute__((ext_vector_type(4))) float f32x4;

__device__ __forceinline__ ushort f2bf(float x) {
    union { float f; uint32_t u; } c; c.f = x;
    const uint32_t u = c.u;
    return (ushort)((u + 0x7fffu + ((u >> 16) & 1u)) >> 16);   // RNE
}
__device__ __forceinline__ float bf2f(ushort h) {
    union { uint32_t u; float f; } c; c.u = ((uint32_t)h) << 16;
    return c.f;
}

#define GLDS16(gp, lp) __builtin_amdgcn_global_load_lds( \
    (const __attribute__((address_space(1))) void*)(gp),  \
    (__attribute__((address_space(3))) void*)(lp), 16, 0, 0)

// ---------------- init ----------------
__global__ void init_kernel(int* acc) {
    if (threadIdx.x == 0 && blockIdx.x == 0) *acc = 0;
}

// ---------------- transpose + split:  in[R][C] -> out[C-chunk][R] (hi,lo bf16) ----------------
// reads cols [cbase, cbase + gridDim.x*32), writes rows [0, gridDim.x*32) of oh/ol (stride R)
__global__ void tsplit_kernel(const float* __restrict__ in, ushort* __restrict__ oh,
                              ushort* __restrict__ ol, int R, int C, int cbase)
{
    __shared__ float tile[32][33];
    const int c0 = blockIdx.x * 32, r0 = blockIdx.y * 32;
    const int tx = threadIdx.x, ty = threadIdx.y;   // (32,8)
    #pragma unroll
    for (int j = 0; j < 32; j += 8)
        tile[ty + j][tx] = in[(size_t)(r0 + ty + j) * C + cbase + c0 + tx];
    __syncthreads();
    #pragma unroll
    for (int j = 0; j < 32; j += 8) {
        const float v = tile[tx][ty + j];
        const ushort h = f2bf(v);
        const size_t idx = (size_t)(c0 + ty + j) * R + r0 + tx;
        oh[idx] = h;
        ol[idx] = f2bf(v - bf2f(h));
    }
}

// ---------------- straight split: f32[n] -> hi,lo bf16[n] ----------------
__global__ void csplit_kernel(const float* __restrict__ in, ushort* __restrict__ oh,
                              ushort* __restrict__ ol, int n)
{
    const int i = (blockIdx.x * 256 + threadIdx.x) * 4;
    if (i >= n) return;
    const float4 f = *(const float4*)&in[i];
    ushort4 h, l;
    h.x = f2bf(f.x); l.x = f2bf(f.x - bf2f(h.x));
    h.y = f2bf(f.y); l.y = f2bf(f.y - bf2f(h.y));
    h.z = f2bf(f.z); l.z = f2bf(f.z - bf2f(h.z));
    h.w = f2bf(f.w); l.w = f2bf(f.w - bf2f(h.w));
    *(ushort4*)&oh[i] = h;
    *(ushort4*)&ol[i] = l;
}

// ---------------- MFMA split-bf16 GEMM ----------------
// C[M,N] = act( (Ah+Al)[M,K] @ (Bh+Bl)^T[N,K] (+bias) ),   3-pass: AhBh + AhBl + AlBh
// 128x128 tile, BK=32, 256 threads (4 waves, 2x2), 4x4 16x16x32 fragments per wave.
// OMODE 0: write f32 to Cf.  OMODE 1: write bf16 hi/lo split to Ch/Cl.
template<int OMODE, bool RELU, bool BIAS>
__global__ __launch_bounds__(256, 2)
void gemm_mfma_kernel(const ushort* __restrict__ Ah, const ushort* __restrict__ Al,
                      const ushort* __restrict__ Bh, const ushort* __restrict__ Bl,
                      const float* __restrict__ bias,
                      float* __restrict__ Cf, ushort* __restrict__ Ch, ushort* __restrict__ Cl,
                      int M, int N, int K)
{
    __shared__ __align__(16) ushort Ahs[128 * 32];
    __shared__ __align__(16) ushort Als[128 * 32];
    __shared__ __align__(16) ushort Bhs[128 * 32];
    __shared__ __align__(16) ushort Bls[128 * 32];

    const int tid  = threadIdx.x;
    const int lane = tid & 63;
    const int w    = tid >> 6;
    const int wr   = w >> 1, wc = w & 1;
    const int bm   = blockIdx.y * 128, bn = blockIdx.x * 128;

    // staging geometry: wave w fills LDS rows [w*32, w*32+32); lane l covers 16B at
    // (row = w*32 + j*16 + l/4, col = (l&3)*8)
    const int    srow  = w * 32 + (lane >> 2);
    const int    scol  = (lane & 3) * 8;
    const size_t aoff0 = (size_t)(bm + srow) * K + scol;
    const size_t boff0 = (size_t)(bn + srow) * K + scol;

    f32x4 acc[4][4];
    #pragma unroll
    for (int m = 0; m < 4; ++m)
        #pragma unroll
        for (int n = 0; n < 4; ++n)
            acc[m][n] = (f32x4)0.0f;

    for (int k0 = 0; k0 < K; k0 += 32) {
        #pragma unroll
        for (int j = 0; j < 2; ++j) {
            const size_t go = (size_t)j * 16 * K + k0;
            const int    lo = w * 1024 + j * 512;        // ushort units
            GLDS16(Ah + aoff0 + go, &Ahs[lo]);
            GLDS16(Al + aoff0 + go, &Als[lo]);
            GLDS16(Bh + boff0 + go, &Bhs[lo]);
            GLDS16(Bl + boff0 + go, &Bls[lo]);
        }
        __syncthreads();   // drains vmcnt: LDS tiles ready

        short8 a_h[4], a_l[4], b_h[4], b_l[4];
        const int ko = (lane >> 4) * 8;
        #pragma unroll
        for (int m = 0; m < 4; ++m) {
            const int off = (wr * 64 + m * 16 + (lane & 15)) * 32 + ko;
            a_h[m] = *(const short8*)&Ahs[off];
            a_l[m] = *(const short8*)&Als[off];
        }
        #pragma unroll
        for (int n = 0; n < 4; ++n) {
            const int off = (wc * 64 + n * 16 + (lane & 15)) * 32 + ko;
            b_h[n] = *(const short8*)&Bhs[off];
            b_l[n] = *(const short8*)&Bls[off];
        }
        #pragma unroll
        for (int m = 0; m < 4; ++m)
            #pragma unroll
            for (int n = 0; n < 4; ++n) {
                acc[m][n] = __builtin_amdgcn_mfma_f32_16x16x32_bf16(a_h[m], b_h[n], acc[m][n], 0, 0, 0);
                acc[m][n] = __builtin_amdgcn_mfma_f32_16x16x32_bf16(a_h[m], b_l[n], acc[m][n], 0, 0, 0);
                acc[m][n] = __builtin_amdgcn_mfma_f32_16x16x32_bf16(a_l[m], b_h[n], acc[m][n], 0, 0, 0);
            }
        __syncthreads();   // all reads done before next stage overwrites
    }

    // epilogue: C/D layout col = lane&15, row = (lane>>4)*4 + q
    const int crow0 = bm + wr * 64 + (lane >> 4) * 4;
    const int ccol0 = bn + wc * 64 + (lane & 15);
    #pragma unroll
    for (int m = 0; m < 4; ++m)
        #pragma unroll
        for (int n = 0; n < 4; ++n) {
            const int col = ccol0 + n * 16;
            const float bv = BIAS ? bias[col] : 0.0f;
            #pragma unroll
            for (int q = 0; q < 4; ++q) {
                float v = acc[m][n][q] + bv;
                if (RELU) v = fmaxf(v, 0.0f);
                const size_t idx = (size_t)(crow0 + m * 16 + q) * N + col;
                if (OMODE == 0) {
                    Cf[idx] = v;
                } else {
                    const ushort h = f2bf(v);
                    Ch[idx] = h;
                    Cl[idx] = f2bf(v - bf2f(h));
                }
            }
        }
}

// ---------------- per-row reduction over one sim chunk (unchanged, validated r1) ----------------
__global__ __launch_bounds__(256) void rowreduce_kernel(
    const float* __restrict__ sim, const int* __restrict__ tgt,
    const float* __restrict__ temp_p, float* __restrict__ perrow,
    int* __restrict__ acc_cnt, int row0)
{
    const int row = blockIdx.x;
    const float* srow = sim + (size_t)row * NTXT_N;
    const int tid = threadIdx.x;

    float v[16];
    #pragma unroll
    for (int q = 0; q < 4; ++q) {
        float4 f = *(const float4*)&srow[4 * tid + 1024 * q];
        v[4 * q + 0] = f.x; v[4 * q + 1] = f.y; v[4 * q + 2] = f.z; v[4 * q + 3] = f.w;
    }

    float ss = 0.0f, mx = -3.4e38f; int mi = 0x7fffffff;
    #pragma unroll
    for (int q = 0; q < 4; ++q)
        #pragma unroll
        for (int r = 0; r < 4; ++r) {
            const int j = 4 * tid + 1024 * q + r;
            const float x = v[4 * q + r];
            ss = fmaf(x, x, ss);
            if (x > mx) { mx = x; mi = j; }
            else if (x == mx && j < mi) mi = j;
        }

    #pragma unroll
    for (int off = 32; off; off >>= 1) {
        ss += __shfl_down(ss, off);
        const float omx = __shfl_down(mx, off);
        const int   omi = __shfl_down(mi, off);
        if (omx > mx || (omx == mx && omi < mi)) { mx = omx; mi = omi; }
    }

    __shared__ float sws[4], swm[4];
    __shared__ int   swi[4];
    __shared__ float bC, bMx;
    __shared__ int   bAmax;
    const int w = tid >> 6, lane = tid & 63;
    if (lane == 0) { sws[w] = ss; swm[w] = mx; swi[w] = mi; }
    __syncthreads();
    if (tid == 0) {
        float tss = 0.0f, tmx = -3.4e38f; int tmi = 0x7fffffff;
        #pragma unroll
        for (int i = 0; i < 4; ++i) {
            tss += sws[i];
            if (swm[i] > tmx || (swm[i] == tmx && swi[i] < tmi)) { tmx = swm[i]; tmi = swi[i]; }
        }
        const float inv_nr = 1.0f / sqrtf(tss);
        const float n2 = sqrtf(tss * inv_nr * inv_nr);   // ~= 1, faithful to reference
        const float Cv = inv_nr / (n2 * temp_p[0]);
        bC = Cv; bMx = tmx * Cv; bAmax = tmi;
    }
    __syncthreads();
    const float Cv = bC, mxx = bMx;

    float es = 0.0f;
    #pragma unroll
    for (int q = 0; q < 16; ++q) es += expf(v[q] * Cv - mxx);
    #pragma unroll
    for (int off = 32; off; off >>= 1) es += __shfl_down(es, off);
    if (lane == 0) sws[w] = es;
    __syncthreads();
    if (tid == 0) {
        const float tes = sws[0] + sws[1] + sws[2] + sws[3];
        const float lse = mxx + logf(tes);
        const int t = tgt[row0 + row];
        perrow[row0 + row] = lse - srow[t] * Cv;
        if (bAmax == t) atomicAdd(acc_cnt, 1);
    }
}

// ---------------- finalize ----------------
__global__ __launch_bounds__(256) void finalize_kernel(
    const float* __restrict__ perrow, const int* __restrict__ acc_cnt,
    float* __restrict__ out)
{
    __shared__ float red[256];
    const int tid = threadIdx.x;
    float s = 0.0f;
    for (int i = tid; i < B_ROWS; i += 256) s += perrow[i];
    red[tid] = s;
    __syncthreads();
    for (int st = 128; st; st >>= 1) {
        if (tid < st) red[tid] += red[tid + st];
        __syncthreads();
    }
    if (tid == 0) {
        out[0] = red[0] / (float)B_ROWS;
        out[1] = (float)(*acc_cnt);
    }
}

extern "C" void kernel_launch(void* const* d_in, const int* in_sizes, int n_in,
                              void* d_out, int out_size, void* d_ws, size_t ws_size,
                              hipStream_t stream)
{
    const float* img  = (const float*)d_in[0];
    const float* txt  = (const float*)d_in[1];
    const int*   tgt  = (const int*)  d_in[2];
    const float* temp = (const float*)d_in[3];
    const float* Wf[6] = { (const float*)d_in[4],  (const float*)d_in[6],  (const float*)d_in[8],
                           (const float*)d_in[10], (const float*)d_in[12], (const float*)d_in[14] };
    const float* bf[6] = { (const float*)d_in[5],  (const float*)d_in[7],  (const float*)d_in[9],
                           (const float*)d_in[11], (const float*)d_in[13], (const float*)d_in[15] };
    float* out = (float*)d_out;

    // weight shapes [K, N] -> transposed hi/lo [N, K]
    const int wK[6] = { D_DIM, H_DIM, H_DIM, D_DIM, H_DIM, H_DIM };
    const int wN[6] = { H_DIM, H_DIM, D_DIM, H_DIM, H_DIM, D_DIM };

    // ---- choose chunk sizes ----
    size_t CH = 4096, SIMCH = 2048;
    auto need = [&](size_t ch, size_t sc) -> size_t {
        size_t wt = 0;
        for (int i = 0; i < 6; ++i) wt += (size_t)wK[i] * wN[i] * 2 * 2;   // hi+lo bf16
        const size_t a0  = ch * H_DIM * 2 * 2;                 // A0 hi/lo (also aliases PIMG)
        const size_t a1  = ch * H_DIM * 2 * 2;                 // A1 hi/lo (also aliases XBUF)
        const size_t pt  = (size_t)NTXT_N * D_DIM * 2 * 2;     // p_txt hi/lo
        const size_t sim = sc * NTXT_N * 4;
        return wt + a0 + a1 + pt + sim + (size_t)B_ROWS * 4 + 4096;
    };
    while (need(CH, SIMCH) > ws_size) {
        if (SIMCH > 1024) SIMCH >>= 1;
        else if (CH > 1024) CH >>= 1;
        else break;
    }

    // ---- carve workspace ----
    uint8_t* p = (uint8_t*)d_ws;
    auto alloc = [&](size_t bytes) -> void* {
        void* r = (void*)p; p += (bytes + 255) & ~(size_t)255; return r;
    };
    ushort* WTh[6]; ushort* WTl[6];
    for (int i = 0; i < 6; ++i) {
        WTh[i] = (ushort*)alloc((size_t)wK[i] * wN[i] * 2);
        WTl[i] = (ushort*)alloc((size_t)wK[i] * wN[i] * 2);
    }
    ushort* A0h = (ushort*)alloc(CH * H_DIM * 2);
    ushort* A0l = (ushort*)alloc(CH * H_DIM * 2);
    ushort* A1h = (ushort*)alloc(CH * H_DIM * 2);
    ushort* A1l = (ushort*)alloc(CH * H_DIM * 2);
    ushort* PTh = (ushort*)alloc((size_t)NTXT_N * D_DIM * 2);
    ushort* PTl = (ushort*)alloc((size_t)NTXT_N * D_DIM * 2);
    float*  SIM = (float*)alloc(SIMCH * NTXT_N * 4);
    float*  PERROW = (float*)alloc((size_t)B_ROWS * 4);
    int*    ACC = (int*)alloc(64);
    // aliases: input chunk (img or txt^T) lives in A1 space; p_img chunk lives in A0 space
    ushort* XBh = A1h;  ushort* XBl = A1l;      // [CH][512] hi/lo
    ushort* PIh = A0h;  ushort* PIl = A0l;      // [CH][512] hi/lo

    init_kernel<<<1, 64, 0, stream>>>(ACC);

    // ---- weight transpose+split ----
    for (int i = 0; i < 6; ++i)
        tsplit_kernel<<<dim3(wN[i] / 32, wK[i] / 32), dim3(32, 8), 0, stream>>>(
            Wf[i], WTh[i], WTl[i], wK[i], wN[i], 0);

    // ---- txt MLP: p_txt = MLP(txt^T), chunked ----
    for (size_t n0 = 0; n0 < NTXT_N; n0 += CH) {
        tsplit_kernel<<<dim3(CH / 32, D_DIM / 32), dim3(32, 8), 0, stream>>>(
            txt, XBh, XBl, D_DIM, NTXT_N, (int)n0);
        gemm_mfma_kernel<1, true, true><<<dim3(H_DIM / 128, CH / 128), 256, 0, stream>>>(
            XBh, XBl, WTh[3], WTl[3], bf[3], nullptr, A0h, A0l, (int)CH, H_DIM, D_DIM);
        gemm_mfma_kernel<1, true, true><<<dim3(H_DIM / 128, CH / 128), 256, 0, stream>>>(
            A0h, A0l, WTh[4], WTl[4], bf[4], nullptr, A1h, A1l, (int)CH, H_DIM, H_DIM);
        gemm_mfma_kernel<1, false, true><<<dim3(D_DIM / 128, CH / 128), 256, 0, stream>>>(
            A1h, A1l, WTh[5], WTl[5], bf[5], nullptr,
            PTh + n0 * D_DIM, PTl + n0 * D_DIM, (int)CH, D_DIM, H_DIM);
    }

    // ---- img MLP + fused sim/loss, chunked ----
    for (size_t m0 = 0; m0 < B_ROWS; m0 += CH) {
        csplit_kernel<<<(CH * D_DIM / 4 + 255) / 256, 256, 0, stream>>>(
            img + m0 * D_DIM, XBh, XBl, (int)(CH * D_DIM));
        gemm_mfma_kernel<1, true, true><<<dim3(H_DIM / 128, CH / 128), 256, 0, stream>>>(
            XBh, XBl, WTh[0], WTl[0], bf[0], nullptr, A0h, A0l, (int)CH, H_DIM, D_DIM);
        gemm_mfma_kernel<1, true, true><<<dim3(H_DIM / 128, CH / 128), 256, 0, stream>>>(
            A0h, A0l, WTh[1], WTl[1], bf[1], nullptr, A1h, A1l, (int)CH, H_DIM, H_DIM);
        gemm_mfma_kernel<1, false, true><<<dim3(D_DIM / 128, CH / 128), 256, 0, stream>>>(
            A1h, A1l, WTh[2], WTl[2], bf[2], nullptr, PIh, PIl, (int)CH, D_DIM, H_DIM);
        for (size_t s0 = 0; s0 < CH; s0 += SIMCH) {
            gemm_mfma_kernel<0, false, false><<<dim3(NTXT_N / 128, SIMCH / 128), 256, 0, stream>>>(
                PIh + s0 * D_DIM, PIl + s0 * D_DIM, PTh, PTl, nullptr,
                SIM, nullptr, nullptr, (int)SIMCH, NTXT_N, D_DIM);
            rowreduce_kernel<<<SIMCH, 256, 0, stream>>>(
                SIM, tgt, temp, PERROW, ACC, (int)(m0 + s0));
        }
    }

    finalize_kernel<<<1, 256, 0, stream>>>(PERROW, ACC, out);
}

// Round 3
// 769.217 us; speedup vs baseline: 3.4516x; 1.3521x over previous
//
#include <hip/hip_runtime.h>
#include <cstdint>
#include <cstddef>

#define B_ROWS 16384
#define D_DIM  512
#define NTXT_N 4096
#define H_DIM  1024

typedef __attribute__((ext_vector_type(8))) short short8;
typedef __attribute__((ext_vector_type(4))) float f32x4;

__device__ __forceinline__ ushort f2bf(float x) {
    union { float f; uint32_t u; } c; c.f = x;
    const uint32_t u = c.u;
    return (ushort)((u + 0x7fffu + ((u >> 16) & 1u)) >> 16);   // RNE
}
__device__ __forceinline__ float bf2f(ushort h) {
    union { uint32_t u; float f; } c; c.u = ((uint32_t)h) << 16;
    return c.f;
}

#define GLDS16(gp, lp) __builtin_amdgcn_global_load_lds( \
    (const __attribute__((address_space(1))) void*)(gp),  \
    (__attribute__((address_space(3))) void*)(lp), 16, 0, 0)

// bijective XCD-aware block remap (T1, m204 formula; MI355X = 8 XCDs)
__device__ __forceinline__ void xcd_remap(int& bx, int& by) {
    const int nx = gridDim.x, ny = gridDim.y;
    const int nwg = nx * ny;
    const int bid = by * nx + bx;
    const int q = nwg >> 3, r = nwg & 7;
    const int xcd = bid & 7, idx = bid >> 3;
    const int nb = (xcd < r ? xcd * (q + 1) : r * (q + 1) + (xcd - r) * q) + idx;
    bx = nb % nx; by = nb / nx;
}

// ---------------- init ----------------
__global__ void init_kernel(int* acc) {
    if (threadIdx.x == 0 && blockIdx.x == 0) *acc = 0;
}

// ---------------- transpose + split:  in[R][C] -> out[C-chunk][R] (hi,lo bf16) ----------------
__global__ void tsplit_kernel(const float* __restrict__ in, ushort* __restrict__ oh,
                              ushort* __restrict__ ol, int R, int C, int cbase)
{
    __shared__ float tile[32][33];
    const int c0 = blockIdx.x * 32, r0 = blockIdx.y * 32;
    const int tx = threadIdx.x, ty = threadIdx.y;   // (32,8)
    #pragma unroll
    for (int j = 0; j < 32; j += 8)
        tile[ty + j][tx] = in[(size_t)(r0 + ty + j) * C + cbase + c0 + tx];
    __syncthreads();
    #pragma unroll
    for (int j = 0; j < 32; j += 8) {
        const float v = tile[tx][ty + j];
        const ushort h = f2bf(v);
        const size_t idx = (size_t)(c0 + ty + j) * R + r0 + tx;
        oh[idx] = h;
        ol[idx] = f2bf(v - bf2f(h));
    }
}

// ---------------- straight split: f32[n] -> hi,lo bf16[n] ----------------
__global__ void csplit_kernel(const float* __restrict__ in, ushort* __restrict__ oh,
                              ushort* __restrict__ ol, int n)
{
    const int i = (blockIdx.x * 256 + threadIdx.x) * 4;
    if (i >= n) return;
    const float4 f = *(const float4*)&in[i];
    ushort4 h, l;
    h.x = f2bf(f.x); l.x = f2bf(f.x - bf2f(h.x));
    h.y = f2bf(f.y); l.y = f2bf(f.y - bf2f(h.y));
    h.z = f2bf(f.z); l.z = f2bf(f.z - bf2f(h.z));
    h.w = f2bf(f.w); l.w = f2bf(f.w - bf2f(h.w));
    *(ushort4*)&oh[i] = h;
    *(ushort4*)&ol[i] = l;
}

// ---------------- MFMA split-bf16 GEMM ----------------
// C[M,N] = act( (Ah+Al)[M,K] @ (Bh+Bl)^T[N,K] (+bias) ),  3-pass: AhBh + AhBl + AlBh
// 128x128 tile, BK=32, 256 threads (4 waves 2x2), 4x4 16x16x32 fragments/wave.
// LDS slot-swizzle: physical slot = logical ^ ((row>>1)&3); staging pre-swizzles
// the GLOBAL source (rule #21: global_load_lds dest must stay linear).
template<int OMODE, bool RELU, bool BIAS>
__global__ __launch_bounds__(256, 2)
void gemm_mfma_kernel(const ushort* __restrict__ Ah, const ushort* __restrict__ Al,
                      const ushort* __restrict__ Bh, const ushort* __restrict__ Bl,
                      const float* __restrict__ bias,
                      float* __restrict__ Cf, ushort* __restrict__ Ch, ushort* __restrict__ Cl,
                      int M, int N, int K)
{
    __shared__ __align__(16) ushort Ahs[128 * 32];
    __shared__ __align__(16) ushort Als[128 * 32];
    __shared__ __align__(16) ushort Bhs[128 * 32];
    __shared__ __align__(16) ushort Bls[128 * 32];

    const int tid  = threadIdx.x;
    const int lane = tid & 63;
    const int w    = tid >> 6;
    const int wr   = w >> 1, wc = w & 1;

    int bxi = blockIdx.x, byi = blockIdx.y;
    xcd_remap(bxi, byi);
    const int bm = byi * 128, bn = bxi * 128;

    // staging: lane l lands at LDS (row = w*32 + j*16 + l>>2, phys slot = l&3);
    // fetch global slot (l&3) ^ sigma(row),  sigma = (row>>1)&3 = (l>>3)&3
    const int    srow  = w * 32 + (lane >> 2);
    const int    scol  = (((lane & 3) ^ ((lane >> 3) & 3)) << 3);   // ushorts
    const size_t aoff0 = (size_t)(bm + srow) * K + scol;
    const size_t boff0 = (size_t)(bn + srow) * K + scol;

    f32x4 acc[4][4];
    #pragma unroll
    for (int m = 0; m < 4; ++m)
        #pragma unroll
        for (int n = 0; n < 4; ++n)
            acc[m][n] = (f32x4)0.0f;

    // fragment-read swizzle constants
    const int frow = lane & 15;                 // row within 16-row fragment
    const int sl   = (frow >> 1) & 3;           // sigma(row)
    const int kslot = (lane >> 4) ^ sl;         // physical slot for logical slot lane>>4
    const int koff  = kslot << 3;               // ushorts

    for (int k0 = 0; k0 < K; k0 += 32) {
        #pragma unroll
        for (int j = 0; j < 2; ++j) {
            const size_t go = (size_t)j * 16 * K + k0;
            const int    lo = w * 1024 + j * 512;        // ushort units
            GLDS16(Ah + aoff0 + go, &Ahs[lo]);
            GLDS16(Al + aoff0 + go, &Als[lo]);
            GLDS16(Bh + boff0 + go, &Bhs[lo]);
            GLDS16(Bl + boff0 + go, &Bls[lo]);
        }
        __syncthreads();   // drains vmcnt: LDS tiles ready

        short8 a_h[4], a_l[4], b_h[4], b_l[4];
        #pragma unroll
        for (int m = 0; m < 4; ++m) {
            const int off = (wr * 64 + m * 16 + frow) * 32 + koff;
            a_h[m] = *(const short8*)&Ahs[off];
            a_l[m] = *(const short8*)&Als[off];
        }
        #pragma unroll
        for (int n = 0; n < 4; ++n) {
            const int off = (wc * 64 + n * 16 + frow) * 32 + koff;
            b_h[n] = *(const short8*)&Bhs[off];
            b_l[n] = *(const short8*)&Bls[off];
        }
        #pragma unroll
        for (int m = 0; m < 4; ++m)
            #pragma unroll
            for (int n = 0; n < 4; ++n) {
                acc[m][n] = __builtin_amdgcn_mfma_f32_16x16x32_bf16(a_h[m], b_h[n], acc[m][n], 0, 0, 0);
                acc[m][n] = __builtin_amdgcn_mfma_f32_16x16x32_bf16(a_h[m], b_l[n], acc[m][n], 0, 0, 0);
                acc[m][n] = __builtin_amdgcn_mfma_f32_16x16x32_bf16(a_l[m], b_h[n], acc[m][n], 0, 0, 0);
            }
        __syncthreads();   // all reads done before next stage overwrites
    }

    // epilogue: C/D layout col = lane&15, row = (lane>>4)*4 + q
    const int crow0 = bm + wr * 64 + (lane >> 4) * 4;
    const int ccol0 = bn + wc * 64 + (lane & 15);
    #pragma unroll
    for (int m = 0; m < 4; ++m)
        #pragma unroll
        for (int n = 0; n < 4; ++n) {
            const int col = ccol0 + n * 16;
            const float bv = BIAS ? bias[col] : 0.0f;
            #pragma unroll
            for (int q = 0; q < 4; ++q) {
                float v = acc[m][n][q] + bv;
                if (RELU) v = fmaxf(v, 0.0f);
                const size_t idx = (size_t)(crow0 + m * 16 + q) * N + col;
                if (OMODE == 0) {
                    Cf[idx] = v;
                } else {
                    const ushort h = f2bf(v);
                    Ch[idx] = h;
                    Cl[idx] = f2bf(v - bf2f(h));
                }
            }
        }
}

// ---------------- per-row reduction over one sim chunk ----------------
__global__ __launch_bounds__(256) void rowreduce_kernel(
    const float* __restrict__ sim, const int* __restrict__ tgt,
    const float* __restrict__ temp_p, float* __restrict__ perrow,
    int* __restrict__ acc_cnt, int row0)
{
    const int row = blockIdx.x;
    const float* srow = sim + (size_t)row * NTXT_N;
    const int tid = threadIdx.x;

    float v[16];
    #pragma unroll
    for (int q = 0; q < 4; ++q) {
        float4 f = *(const float4*)&srow[4 * tid + 1024 * q];
        v[4 * q + 0] = f.x; v[4 * q + 1] = f.y; v[4 * q + 2] = f.z; v[4 * q + 3] = f.w;
    }

    float ss = 0.0f, mx = -3.4e38f; int mi = 0x7fffffff;
    #pragma unroll
    for (int q = 0; q < 4; ++q)
        #pragma unroll
        for (int r = 0; r < 4; ++r) {
            const int j = 4 * tid + 1024 * q + r;
            const float x = v[4 * q + r];
            ss = fmaf(x, x, ss);
            if (x > mx) { mx = x; mi = j; }
            else if (x == mx && j < mi) mi = j;
        }

    #pragma unroll
    for (int off = 32; off; off >>= 1) {
        ss += __shfl_down(ss, off);
        const float omx = __shfl_down(mx, off);
        const int   omi = __shfl_down(mi, off);
        if (omx > mx || (omx == mx && omi < mi)) { mx = omx; mi = omi; }
    }

    __shared__ float sws[4], swm[4];
    __shared__ int   swi[4];
    __shared__ float bC, bMx;
    __shared__ int   bAmax;
    const int w = tid >> 6, lane = tid & 63;
    if (lane == 0) { sws[w] = ss; swm[w] = mx; swi[w] = mi; }
    __syncthreads();
    if (tid == 0) {
        float tss = 0.0f, tmx = -3.4e38f; int tmi = 0x7fffffff;
        #pragma unroll
        for (int i = 0; i < 4; ++i) {
            tss += sws[i];
            if (swm[i] > tmx || (swm[i] == tmx && swi[i] < tmi)) { tmx = swm[i]; tmi = swi[i]; }
        }
        const float inv_nr = 1.0f / sqrtf(tss);
        const float n2 = sqrtf(tss * inv_nr * inv_nr);   // ~= 1, faithful to reference
        const float Cv = inv_nr / (n2 * temp_p[0]);
        bC = Cv; bMx = tmx * Cv; bAmax = tmi;
    }
    __syncthreads();
    const float Cv = bC, mxx = bMx;

    float es = 0.0f;
    #pragma unroll
    for (int q = 0; q < 16; ++q) es += expf(v[q] * Cv - mxx);
    #pragma unroll
    for (int off = 32; off; off >>= 1) es += __shfl_down(es, off);
    if (lane == 0) sws[w] = es;
    __syncthreads();
    if (tid == 0) {
        const float tes = sws[0] + sws[1] + sws[2] + sws[3];
        const float lse = mxx + logf(tes);
        const int t = tgt[row0 + row];
        perrow[row0 + row] = lse - srow[t] * Cv;
        if (bAmax == t) atomicAdd(acc_cnt, 1);
    }
}

// ---------------- finalize ----------------
__global__ __launch_bounds__(256) void finalize_kernel(
    const float* __restrict__ perrow, const int* __restrict__ acc_cnt,
    float* __restrict__ out)
{
    __shared__ float red[256];
    const int tid = threadIdx.x;
    float s = 0.0f;
    for (int i = tid; i < B_ROWS; i += 256) s += perrow[i];
    red[tid] = s;
    __syncthreads();
    for (int st = 128; st; st >>= 1) {
        if (tid < st) red[tid] += red[tid + st];
        __syncthreads();
    }
    if (tid == 0) {
        out[0] = red[0] / (float)B_ROWS;
        out[1] = (float)(*acc_cnt);
    }
}

extern "C" void kernel_launch(void* const* d_in, const int* in_sizes, int n_in,
                              void* d_out, int out_size, void* d_ws, size_t ws_size,
                              hipStream_t stream)
{
    const float* img  = (const float*)d_in[0];
    const float* txt  = (const float*)d_in[1];
    const int*   tgt  = (const int*)  d_in[2];
    const float* temp = (const float*)d_in[3];
    const float* Wf[6] = { (const float*)d_in[4],  (const float*)d_in[6],  (const float*)d_in[8],
                           (const float*)d_in[10], (const float*)d_in[12], (const float*)d_in[14] };
    const float* bf[6] = { (const float*)d_in[5],  (const float*)d_in[7],  (const float*)d_in[9],
                           (const float*)d_in[11], (const float*)d_in[13], (const float*)d_in[15] };
    float* out = (float*)d_out;

    // weight shapes [K, N] -> transposed hi/lo [N, K]
    const int wK[6] = { D_DIM, H_DIM, H_DIM, D_DIM, H_DIM, H_DIM };
    const int wN[6] = { H_DIM, H_DIM, D_DIM, H_DIM, H_DIM, D_DIM };

    // ---- choose chunk sizes: prefer big M for occupancy (grid >= 2 blocks/CU) ----
    auto need = [&](size_t ch, size_t sc) -> size_t {
        size_t wt = 0;
        for (int i = 0; i < 6; ++i) wt += (size_t)wK[i] * wN[i] * 2 * 2;
        const size_t a01 = 2 * (ch * H_DIM * 2 * 2);
        const size_t pt  = (size_t)NTXT_N * D_DIM * 2 * 2;
        const size_t sim = sc * NTXT_N * 4;
        return wt + a01 + pt + sim + (size_t)B_ROWS * 4 + (size_t)64 * 1024;
    };
    const size_t ladder[][2] = { {16384, 4096}, {16384, 2048}, {8192, 4096}, {8192, 2048},
                                 {4096, 2048},  {4096, 1024},  {2048, 1024}, {1024, 1024} };
    size_t CH = 1024, SIMCH = 512;
    for (auto& e : ladder)
        if (need(e[0], e[1]) <= ws_size) { CH = e[0]; SIMCH = e[1]; break; }

    // ---- carve workspace ----
    uint8_t* p = (uint8_t*)d_ws;
    auto alloc = [&](size_t bytes) -> void* {
        void* r = (void*)p; p += (bytes + 255) & ~(size_t)255; return r;
    };
    ushort* WTh[6]; ushort* WTl[6];
    for (int i = 0; i < 6; ++i) {
        WTh[i] = (ushort*)alloc((size_t)wK[i] * wN[i] * 2);
        WTl[i] = (ushort*)alloc((size_t)wK[i] * wN[i] * 2);
    }
    ushort* A0h = (ushort*)alloc(CH * H_DIM * 2);
    ushort* A0l = (ushort*)alloc(CH * H_DIM * 2);
    ushort* A1h = (ushort*)alloc(CH * H_DIM * 2);
    ushort* A1l = (ushort*)alloc(CH * H_DIM * 2);
    ushort* PTh = (ushort*)alloc((size_t)NTXT_N * D_DIM * 2);
    ushort* PTl = (ushort*)alloc((size_t)NTXT_N * D_DIM * 2);
    float*  SIM = (float*)alloc(SIMCH * NTXT_N * 4);
    float*  PERROW = (float*)alloc((size_t)B_ROWS * 4);
    int*    ACC = (int*)alloc(64);
    ushort* XBh = A1h;  ushort* XBl = A1l;      // input chunk alias
    ushort* PIh = A0h;  ushort* PIl = A0l;      // p_img chunk alias

    init_kernel<<<1, 64, 0, stream>>>(ACC);

    // ---- weight transpose+split ----
    for (int i = 0; i < 6; ++i)
        tsplit_kernel<<<dim3(wN[i] / 32, wK[i] / 32), dim3(32, 8), 0, stream>>>(
            Wf[i], WTh[i], WTl[i], wK[i], wN[i], 0);

    // ---- txt MLP: p_txt = MLP(txt^T), chunked ----
    const size_t CHT = CH < (size_t)NTXT_N ? CH : (size_t)NTXT_N;
    for (size_t n0 = 0; n0 < NTXT_N; n0 += CHT) {
        tsplit_kernel<<<dim3(CHT / 32, D_DIM / 32), dim3(32, 8), 0, stream>>>(
            txt, XBh, XBl, D_DIM, NTXT_N, (int)n0);
        gemm_mfma_kernel<1, true, true><<<dim3(H_DIM / 128, CHT / 128), 256, 0, stream>>>(
            XBh, XBl, WTh[3], WTl[3], bf[3], nullptr, A0h, A0l, (int)CHT, H_DIM, D_DIM);
        gemm_mfma_kernel<1, true, true><<<dim3(H_DIM / 128, CHT / 128), 256, 0, stream>>>(
            A0h, A0l, WTh[4], WTl[4], bf[4], nullptr, A1h, A1l, (int)CHT, H_DIM, H_DIM);
        gemm_mfma_kernel<1, false, true><<<dim3(D_DIM / 128, CHT / 128), 256, 0, stream>>>(
            A1h, A1l, WTh[5], WTl[5], bf[5], nullptr,
            PTh + n0 * D_DIM, PTl + n0 * D_DIM, (int)CHT, D_DIM, H_DIM);
    }

    // ---- img MLP + fused sim/loss, chunked ----
    for (size_t m0 = 0; m0 < B_ROWS; m0 += CH) {
        csplit_kernel<<<(CH * D_DIM / 4 + 255) / 256, 256, 0, stream>>>(
            img + m0 * D_DIM, XBh, XBl, (int)(CH * D_DIM));
        gemm_mfma_kernel<1, true, true><<<dim3(H_DIM / 128, CH / 128), 256, 0, stream>>>(
            XBh, XBl, WTh[0], WTl[0], bf[0], nullptr, A0h, A0l, (int)CH, H_DIM, D_DIM);
        gemm_mfma_kernel<1, true, true><<<dim3(H_DIM / 128, CH / 128), 256, 0, stream>>>(
            A0h, A0l, WTh[1], WTl[1], bf[1], nullptr, A1h, A1l, (int)CH, H_DIM, H_DIM);
        gemm_mfma_kernel<1, false, true><<<dim3(D_DIM / 128, CH / 128), 256, 0, stream>>>(
            A1h, A1l, WTh[2], WTl[2], bf[2], nullptr, PIh, PIl, (int)CH, D_DIM, H_DIM);
        for (size_t s0 = 0; s0 < CH; s0 += SIMCH) {
            gemm_mfma_kernel<0, false, false><<<dim3(NTXT_N / 128, SIMCH / 128), 256, 0, stream>>>(
                PIh + s0 * D_DIM, PIl + s0 * D_DIM, PTh, PTl, nullptr,
                SIM, nullptr, nullptr, (int)SIMCH, NTXT_N, D_DIM);
            rowreduce_kernel<<<SIMCH, 256, 0, stream>>>(
                SIM, tgt, temp, PERROW, ACC, (int)(m0 + s0));
        }
    }

    finalize_kernel<<<1, 256, 0, stream>>>(PERROW, ACC, out);
}